// Round 12
// baseline (596.895 us; speedup 1.0000x reference)
//
#include <hip/hip_runtime.h>

#define TLEN  1024
#define HN    64
#define LOG2E 1.4426950408889634f

// clang builtins use __fp16 vectors, NOT _Float16.
typedef __fp16 half2v __attribute__((ext_vector_type(2)));
typedef __fp16 half8v __attribute__((ext_vector_type(8)));
typedef float  float4v __attribute__((ext_vector_type(4)));

// One wave / batch element, 1024 blocks. DUAL-PIPE hh matvec:
//  * R11 post-mortem: 32 MFMA/step saturate the PER-SIMD matrix pipe
//    (~19.4 cy each => 560 cy), then a ~600 cy act/LDS tail while the pipe
//    idles -- matvec wastes 15/16 of M (replicated rows). R3's pure-VALU
//    wall was ~960 busy cy. Both pipes alone land ~510-525 us.
//  * This kernel splits BY GATE: i,f on the matrix pipe (8 tiles x 2
//    K-halves = 16 MFMA ~= 310 matrix cy, R11's verified replicated-A
//    layout + rg-cndmask select), g,o on the VALU (64 fdot2 ~= 256 issue
//    cy, R3's verified chains) ISSUED WHILE the MFMAs crunch -- MFMA holds
//    the matrix pipe ~19cy but frees the issue port, so fdot2s overlap.
//  * h broadcast: 8 uniform ds_read_b128 of hbuf (conflict-free broadcast,
//    verified R11) deliver adjacent pairs {h[2P],h[2P+1]} in LINEAR memory
//    order -- no permutation primitives (R4-R6 lesson), no readlanes
//    (R3's 256cy), no bpermute storm (R7's regression). fdot2 weights are
//    gathered to match: {w[2P], w[2P+1]} (init-only).
//  * A-fragments for MFMA: 2 more ds_read_b128 at rg*8 / 32+rg*8 (4
//    distinct 16B slices -> disjoint banks, conflict-free; R11 verified).
// All pieces HW-verified by passing rounds; new = combination + adjacent
// pair gather. hbuf WAR safe single-wave (in-order LDS, R11).
// Carried EXACTLY: x staged 64 steps/chunk + 2 readlane broadcasts, 8
// x-fdot2 with pre-scaled f16 weights/biases (log2e folded, 2*log2e tanh),
// exp2+rcp activations, FC ring[64][65] + epilogue, h published f16 RTZ.

#define FOR8(X)  X(0) X(1) X(2) X(3) X(4) X(5) X(6) X(7)
#define FOR32(X) \
    X(0) X(1) X(2) X(3) X(4) X(5) X(6) X(7) \
    X(8) X(9) X(10) X(11) X(12) X(13) X(14) X(15) \
    X(16) X(17) X(18) X(19) X(20) X(21) X(22) X(23) \
    X(24) X(25) X(26) X(27) X(28) X(29) X(30) X(31)

__global__ __launch_bounds__(64, 1)
void lstm_dual(const float* __restrict__ x,      // [B, T, 4]
               const float* __restrict__ W_ih,   // [256, 4]
               const float* __restrict__ W_hh,   // [256, 64]
               const float* __restrict__ b_ih,   // [256]
               const float* __restrict__ b_hh,   // [256]
               const float* __restrict__ W_fc,   // [1, 64]
               const float* __restrict__ b_fc,   // [1]
               float* __restrict__ out)          // [B, T]
{
    const int b   = blockIdx.x;
    const int l   = threadIdx.x;   // lane; unit for act/x/FC
    const int col = l & 15;        // B col / D col
    const int rg  = l >> 4;        // k-group; D row-group (replicated rows)

    __shared__ float ring[64][65];                    // FC partials
    __shared__ alignas(16) unsigned short hbuf[HN];   // h_t as f16

    hbuf[l] = 0;   // h_0 = 0 (single wave: in-order LDS)

    // ---- MFMA B-fragments: gates i (tiles 0-3) + f (tiles 4-7) ----
    // wb_t_kh[j] = W_hh[t*16+col][kh*32 + rg*8 + j] * LOG2E
#define DECLW(t) half8v wb##t##_0, wb##t##_1;
    FOR8(DECLW)
#undef DECLW

#define LOADW(t) { \
    const float* wr = W_hh + ((t) * 16 + col) * HN + rg * 8; \
    wb##t##_0[0] = (__fp16)(wr[0] * LOG2E);  wb##t##_0[1] = (__fp16)(wr[1] * LOG2E); \
    wb##t##_0[2] = (__fp16)(wr[2] * LOG2E);  wb##t##_0[3] = (__fp16)(wr[3] * LOG2E); \
    wb##t##_0[4] = (__fp16)(wr[4] * LOG2E);  wb##t##_0[5] = (__fp16)(wr[5] * LOG2E); \
    wb##t##_0[6] = (__fp16)(wr[6] * LOG2E);  wb##t##_0[7] = (__fp16)(wr[7] * LOG2E); \
    wb##t##_1[0] = (__fp16)(wr[32] * LOG2E); wb##t##_1[1] = (__fp16)(wr[33] * LOG2E); \
    wb##t##_1[2] = (__fp16)(wr[34] * LOG2E); wb##t##_1[3] = (__fp16)(wr[35] * LOG2E); \
    wb##t##_1[4] = (__fp16)(wr[36] * LOG2E); wb##t##_1[5] = (__fp16)(wr[37] * LOG2E); \
    wb##t##_1[6] = (__fp16)(wr[38] * LOG2E); wb##t##_1[7] = (__fp16)(wr[39] * LOG2E); \
    asm volatile("" : "+v"(wb##t##_0), "+v"(wb##t##_1)); }
    FOR8(LOADW)
#undef LOADW

    // ---- fdot2 weights: gates g (2*log2e) and o (log2e), ADJACENT pairs
    //      {w[2P], w[2P+1]} to match the linear LDS pair reads ----
    const float* wr_g = W_hh + (2 * HN + l) * HN;
    const float* wr_o = W_hh + (3 * HN + l) * HN;
#define DECLP(P) half2v pg##P, po##P;
    FOR32(DECLP)
#undef DECLP
#define LOADP(P) \
    pg##P = __builtin_amdgcn_cvt_pkrtz(wr_g[2 * (P)] * (2.0f * LOG2E), \
                                       wr_g[2 * (P) + 1] * (2.0f * LOG2E)); \
    po##P = __builtin_amdgcn_cvt_pkrtz(wr_o[2 * (P)] * LOG2E, \
                                       wr_o[2 * (P) + 1] * LOG2E); \
    asm volatile("" : "+v"(pg##P), "+v"(po##P));
    FOR32(LOADP)
#undef LOADP

    // ---- x-weights (unit l), pre-scaled; 2 half2 per gate (as R3) ----
    half2v wip0 = __builtin_amdgcn_cvt_pkrtz(W_ih[(0 * HN + l) * 4 + 0] * LOG2E,
                                             W_ih[(0 * HN + l) * 4 + 1] * LOG2E);
    half2v wip1 = __builtin_amdgcn_cvt_pkrtz(W_ih[(0 * HN + l) * 4 + 2] * LOG2E,
                                             W_ih[(0 * HN + l) * 4 + 3] * LOG2E);
    half2v wfp0 = __builtin_amdgcn_cvt_pkrtz(W_ih[(1 * HN + l) * 4 + 0] * LOG2E,
                                             W_ih[(1 * HN + l) * 4 + 1] * LOG2E);
    half2v wfp1 = __builtin_amdgcn_cvt_pkrtz(W_ih[(1 * HN + l) * 4 + 2] * LOG2E,
                                             W_ih[(1 * HN + l) * 4 + 3] * LOG2E);
    half2v wgp0 = __builtin_amdgcn_cvt_pkrtz(W_ih[(2 * HN + l) * 4 + 0] * 2.0f * LOG2E,
                                             W_ih[(2 * HN + l) * 4 + 1] * 2.0f * LOG2E);
    half2v wgp1 = __builtin_amdgcn_cvt_pkrtz(W_ih[(2 * HN + l) * 4 + 2] * 2.0f * LOG2E,
                                             W_ih[(2 * HN + l) * 4 + 3] * 2.0f * LOG2E);
    half2v wop0 = __builtin_amdgcn_cvt_pkrtz(W_ih[(3 * HN + l) * 4 + 0] * LOG2E,
                                             W_ih[(3 * HN + l) * 4 + 1] * LOG2E);
    half2v wop1 = __builtin_amdgcn_cvt_pkrtz(W_ih[(3 * HN + l) * 4 + 2] * LOG2E,
                                             W_ih[(3 * HN + l) * 4 + 3] * LOG2E);

    const float bias_i = (b_ih[0 * HN + l] + b_hh[0 * HN + l]) * LOG2E;
    const float bias_f = (b_ih[1 * HN + l] + b_hh[1 * HN + l]) * LOG2E;
    const float bias_g = (b_ih[2 * HN + l] + b_hh[2 * HN + l]) * (2.0f * LOG2E);
    const float bias_o = (b_ih[3 * HN + l] + b_hh[3 * HN + l]) * LOG2E;
    const float wfc = W_fc[l];
    const float bfc = b_fc[0];

    const bool rb0 = (rg & 1) != 0;   // tile-select bits
    const bool rb1 = (rg & 2) != 0;

    const float* xb = x   + (size_t)b * TLEN * 4;
    float*       ob = out + (size_t)b * TLEN;

    float h = 0.0f, c = 0.0f;
    const float4v zf = {0.0f, 0.0f, 0.0f, 0.0f};

    // ---- x stage: lane l holds x[t0 + l] (16B coalesced per chunk) ----
    float4 xcur = *(const float4*)(xb + (size_t)l * 4);   // chunk 0

    for (int ci = 0; ci < TLEN / 64; ++ci) {
        const int cn = (ci < TLEN / 64 - 1) ? ci + 1 : ci;
        float4 xnext = *(const float4*)(xb + (size_t)(cn * 64 + l) * 4);

        const int xq0 = __builtin_bit_cast(int, __builtin_amdgcn_cvt_pkrtz(xcur.x, xcur.y));
        const int xq1 = __builtin_bit_cast(int, __builtin_amdgcn_cvt_pkrtz(xcur.z, xcur.w));

        for (int s = 0; s < 64; ++s) {
            // ---- A-fragments (per-rg 16B slices; 4 distinct -> no conflict)
            const half8v a0 = *(const half8v*)&hbuf[rg * 8];
            const half8v a1 = *(const half8v*)&hbuf[32 + rg * 8];
            // ---- pair reads: h as 32 half2, uniform broadcast ----
            const uint4 q0 = *(const uint4*)&hbuf[0];
            const uint4 q1 = *(const uint4*)&hbuf[8];
            const uint4 q2 = *(const uint4*)&hbuf[16];
            const uint4 q3 = *(const uint4*)&hbuf[24];
            const uint4 q4 = *(const uint4*)&hbuf[32];
            const uint4 q5 = *(const uint4*)&hbuf[40];
            const uint4 q6 = *(const uint4*)&hbuf[48];
            const uint4 q7 = *(const uint4*)&hbuf[56];

            // ---- MFMA i,f: issue first, crunches under the fdot2s ----
#define MM(t) \
            float4v d##t = __builtin_amdgcn_mfma_f32_16x16x32_f16(a0, wb##t##_0, zf, 0, 0, 0); \
            d##t = __builtin_amdgcn_mfma_f32_16x16x32_f16(a1, wb##t##_1, d##t, 0, 0, 0);
            FOR8(MM)
#undef MM

            // ---- x broadcast + x-dot chains (all 4 gates, biases in C) ----
            const int xi0 = __builtin_amdgcn_readlane(xq0, s);
            const int xi1 = __builtin_amdgcn_readlane(xq1, s);
            const half2v xh0 = __builtin_bit_cast(half2v, xi0);
            const half2v xh1 = __builtin_bit_cast(half2v, xi1);

            float ai = __builtin_amdgcn_fdot2(wip0, xh0, bias_i, false);
            float af = __builtin_amdgcn_fdot2(wfp0, xh0, bias_f, false);
            float agE = __builtin_amdgcn_fdot2(wgp0, xh0, bias_g, false);
            float aoE = __builtin_amdgcn_fdot2(wop0, xh0, bias_o, false);
            ai = __builtin_amdgcn_fdot2(wip1, xh1, ai, false);
            af = __builtin_amdgcn_fdot2(wfp1, xh1, af, false);
            agE = __builtin_amdgcn_fdot2(wgp1, xh1, agE, false);
            aoE = __builtin_amdgcn_fdot2(wop1, xh1, aoE, false);
            float agO = 0.0f, aoO = 0.0f;

            // ---- g,o on the VALU: 64 fdot2, 4 chains, pairs from q ----
#define GOB(q, P0, P1, P2, P3, AG, AO) { \
            const half2v hA = __builtin_bit_cast(half2v, (int)(q).x); \
            const half2v hB = __builtin_bit_cast(half2v, (int)(q).y); \
            const half2v hC = __builtin_bit_cast(half2v, (int)(q).z); \
            const half2v hD = __builtin_bit_cast(half2v, (int)(q).w); \
            AG = __builtin_amdgcn_fdot2(pg##P0, hA, AG, false); \
            AO = __builtin_amdgcn_fdot2(po##P0, hA, AO, false); \
            AG = __builtin_amdgcn_fdot2(pg##P1, hB, AG, false); \
            AO = __builtin_amdgcn_fdot2(po##P1, hB, AO, false); \
            AG = __builtin_amdgcn_fdot2(pg##P2, hC, AG, false); \
            AO = __builtin_amdgcn_fdot2(po##P2, hC, AO, false); \
            AG = __builtin_amdgcn_fdot2(pg##P3, hD, AG, false); \
            AO = __builtin_amdgcn_fdot2(po##P3, hD, AO, false); }
            GOB(q0, 0, 1, 2, 3,     agE, aoE)
            GOB(q4, 16, 17, 18, 19, agO, aoO)
            GOB(q1, 4, 5, 6, 7,     agE, aoE)
            GOB(q5, 20, 21, 22, 23, agO, aoO)
            GOB(q2, 8, 9, 10, 11,   agE, aoE)
            GOB(q6, 24, 25, 26, 27, agO, aoO)
            GOB(q3, 12, 13, 14, 15, agE, aoE)
            GOB(q7, 28, 29, 30, 31, agO, aoO)
#undef GOB
            const float ag = agE + agO;
            const float ao = aoE + aoO;

            // ---- select i,f from MFMA tiles (R11-verified pattern) ----
            {
                const float i01 = rb0 ? d1[0] : d0[0];
                const float i23 = rb0 ? d3[0] : d2[0];
                ai += rb1 ? i23 : i01;
                const float f01 = rb0 ? d5[0] : d4[0];
                const float f23 = rb0 ? d7[0] : d6[0];
                af += rb1 ? f23 : f01;
            }

            // ---- activations (pre-scaled): sigmoid/tanh via exp2+rcp ----
            float si = __builtin_amdgcn_rcpf(1.0f + __builtin_amdgcn_exp2f(-ai));
            float sf = __builtin_amdgcn_rcpf(1.0f + __builtin_amdgcn_exp2f(-af));
            float tg = 1.0f - 2.0f * __builtin_amdgcn_rcpf(
                                         1.0f + __builtin_amdgcn_exp2f(ag));
            float so = __builtin_amdgcn_rcpf(1.0f + __builtin_amdgcn_exp2f(-ao));

            c = sf * c + si * tg;
            float th = 1.0f - 2.0f * __builtin_amdgcn_rcpf(
                           1.0f + __builtin_amdgcn_exp2f(c * (2.0f * LOG2E)));
            h = so * th;

            // ---- publish h (f16 RTZ) + FC partial ----
            const int hpk = __builtin_bit_cast(int,
                                __builtin_amdgcn_cvt_pkrtz(h, h));
            hbuf[l] = (unsigned short)(hpk & 0xffff);
            ring[s][l] = h * wfc;
        }

        // ---- FC: transposed reduce + coalesced 64-wide store ----
        __syncthreads();   // single wave: orders LDS w->r
        float s0 = 0.f, s1 = 0.f, s2 = 0.f, s3 = 0.f;
#pragma unroll
        for (int k = 0; k < HN; k += 4) {
            s0 += ring[l][k];
            s1 += ring[l][k + 1];
            s2 += ring[l][k + 2];
            s3 += ring[l][k + 3];
        }
        ob[ci * 64 + l] = (s0 + s1) + (s2 + s3) + bfc;

        xcur = xnext;
    }
}

extern "C" void kernel_launch(void* const* d_in, const int* in_sizes, int n_in,
                              void* d_out, int out_size, void* d_ws, size_t ws_size,
                              hipStream_t stream) {
    const float* x    = (const float*)d_in[0];
    const float* W_ih = (const float*)d_in[1];
    const float* W_hh = (const float*)d_in[2];
    const float* b_ih = (const float*)d_in[3];
    const float* b_hh = (const float*)d_in[4];
    const float* W_fc = (const float*)d_in[5];
    const float* b_fc = (const float*)d_in[6];
    float* out = (float*)d_out;

    const int B = in_sizes[0] / (TLEN * 4);   // 1024
    lstm_dual<<<dim3(B), dim3(64), 0, stream>>>(
        x, W_ih, W_hh, b_ih, b_hh, W_fc, b_fc, out);
}

// Round 13
// 525.132 us; speedup vs baseline: 1.1367x; 1.1367x over previous
//
#include <hip/hip_runtime.h>

#define TLEN  1024
#define HN    64
#define LOG2E 1.4426950408889634f

// clang builtins use __fp16 vectors, NOT _Float16.
typedef __fp16 half2v __attribute__((ext_vector_type(2)));
typedef __fp16 half8v __attribute__((ext_vector_type(8)));
typedef float  float4v __attribute__((ext_vector_type(4)));

// One wave / batch element, 1024 blocks. R11 base (MFMA hh matvec with
// replicated-A / W^T-as-B / rg-cndmask select -- all layouts HW-verified)
// with ONE change: GATE-GRANULAR INTERLEAVE of MFMA issue and activations.
//
// R11 post-mortem: wall 1190 cy/step = 560 matrix (32 MFMA x 19.4cy, the
// per-SIMD ceiling) + ~280 real-VALU + ~350 exposed serial latency; acts
// sat entirely AFTER the matrix phase. R12 (gate-split dual-pipe) made it
// worse (587us): pipes ran serially AND g/o cost more VALU than saved.
//
// Dependency fact: gate G's select needs only tiles G*4..G*4+3 (t=G*4+rg).
// So: issue groups 0,1 (16 MFMA) -> compute sigmoid-i (needs d0-3, ready
// ~155cy in while group-1 crunches) -> issue group 2 -> sigmoid-f ->
// issue group 3 -> tanh-g -> o-select + c/h tail after the last tile.
// si/sf/tg (~150cy VALU+trans) hide under the 620cy matrix phase; only
// the ~100cy tail stays serial. Ideal wall ~760cy vs R11's 1190.
// Math is BIT-IDENTICAL to R11 (same ops, same order per chain) =>
// absmax must be exactly 0.0009765625 (tripwire).
//
// Carried from R11 verbatim: A = h replicated (2 uniform ds_read_b128 of
// hbuf, conflict-free broadcast), B = W_hh^T fragments (lane holds
// W[t*16+col][k-slice], k formula matches A's => k-order cancels), D
// select = 3 cndmask/gate via rb0/rb1, x staged 64 steps/chunk + 2
// readlane broadcasts, 8 x-fdot2 (pre-scaled f16, log2e folded, 2*log2e
// tanh), exp2+rcp activations, FC ring[64][65] + epilogue, h published
// f16 RTZ, hbuf WAR safe single-wave (in-order LDS).

#define FOR16(X) \
    X(0) X(1) X(2) X(3) X(4) X(5) X(6) X(7) \
    X(8) X(9) X(10) X(11) X(12) X(13) X(14) X(15)

__global__ __launch_bounds__(64, 1)
void lstm_mfma3(const float* __restrict__ x,      // [B, T, 4]
                const float* __restrict__ W_ih,   // [256, 4]
                const float* __restrict__ W_hh,   // [256, 64]
                const float* __restrict__ b_ih,   // [256]
                const float* __restrict__ b_hh,   // [256]
                const float* __restrict__ W_fc,   // [1, 64]
                const float* __restrict__ b_fc,   // [1]
                float* __restrict__ out)          // [B, T]
{
    const int b   = blockIdx.x;
    const int l   = threadIdx.x;   // lane; unit for act/x/FC
    const int col = l & 15;        // B col / D col
    const int rg  = l >> 4;        // k-group; D row-group (replicated rows)

    __shared__ float ring[64][65];                    // FC partials
    __shared__ alignas(16) unsigned short hbuf[HN];   // h_t as f16

    hbuf[l] = 0;   // h_0 = 0 (single wave: in-order LDS, no barrier)

    // ---- B fragments: 16 tiles x 2 K-halves, W rows as COLUMNS ----
#define DECLW(t) half8v wb##t##_0, wb##t##_1;
    FOR16(DECLW)
#undef DECLW

#define LOADW(t) { \
    const float sc = (((t) >> 2) == 2) ? (2.0f * LOG2E) : LOG2E; \
    const float* wr = W_hh + ((t) * 16 + col) * HN + rg * 8; \
    wb##t##_0[0] = (__fp16)(wr[0] * sc);  wb##t##_0[1] = (__fp16)(wr[1] * sc); \
    wb##t##_0[2] = (__fp16)(wr[2] * sc);  wb##t##_0[3] = (__fp16)(wr[3] * sc); \
    wb##t##_0[4] = (__fp16)(wr[4] * sc);  wb##t##_0[5] = (__fp16)(wr[5] * sc); \
    wb##t##_0[6] = (__fp16)(wr[6] * sc);  wb##t##_0[7] = (__fp16)(wr[7] * sc); \
    wb##t##_1[0] = (__fp16)(wr[32] * sc); wb##t##_1[1] = (__fp16)(wr[33] * sc); \
    wb##t##_1[2] = (__fp16)(wr[34] * sc); wb##t##_1[3] = (__fp16)(wr[35] * sc); \
    wb##t##_1[4] = (__fp16)(wr[36] * sc); wb##t##_1[5] = (__fp16)(wr[37] * sc); \
    wb##t##_1[6] = (__fp16)(wr[38] * sc); wb##t##_1[7] = (__fp16)(wr[39] * sc); \
    asm volatile("" : "+v"(wb##t##_0), "+v"(wb##t##_1)); }
    FOR16(LOADW)
#undef LOADW

    // ---- x-weights (unit l), pre-scaled; 2 half2 per gate ----
    half2v wip0 = __builtin_amdgcn_cvt_pkrtz(W_ih[(0 * HN + l) * 4 + 0] * LOG2E,
                                             W_ih[(0 * HN + l) * 4 + 1] * LOG2E);
    half2v wip1 = __builtin_amdgcn_cvt_pkrtz(W_ih[(0 * HN + l) * 4 + 2] * LOG2E,
                                             W_ih[(0 * HN + l) * 4 + 3] * LOG2E);
    half2v wfp0 = __builtin_amdgcn_cvt_pkrtz(W_ih[(1 * HN + l) * 4 + 0] * LOG2E,
                                             W_ih[(1 * HN + l) * 4 + 1] * LOG2E);
    half2v wfp1 = __builtin_amdgcn_cvt_pkrtz(W_ih[(1 * HN + l) * 4 + 2] * LOG2E,
                                             W_ih[(1 * HN + l) * 4 + 3] * LOG2E);
    half2v wgp0 = __builtin_amdgcn_cvt_pkrtz(W_ih[(2 * HN + l) * 4 + 0] * 2.0f * LOG2E,
                                             W_ih[(2 * HN + l) * 4 + 1] * 2.0f * LOG2E);
    half2v wgp1 = __builtin_amdgcn_cvt_pkrtz(W_ih[(2 * HN + l) * 4 + 2] * 2.0f * LOG2E,
                                             W_ih[(2 * HN + l) * 4 + 3] * 2.0f * LOG2E);
    half2v wop0 = __builtin_amdgcn_cvt_pkrtz(W_ih[(3 * HN + l) * 4 + 0] * LOG2E,
                                             W_ih[(3 * HN + l) * 4 + 1] * LOG2E);
    half2v wop1 = __builtin_amdgcn_cvt_pkrtz(W_ih[(3 * HN + l) * 4 + 2] * LOG2E,
                                             W_ih[(3 * HN + l) * 4 + 3] * LOG2E);

    const float bias_i = (b_ih[0 * HN + l] + b_hh[0 * HN + l]) * LOG2E;
    const float bias_f = (b_ih[1 * HN + l] + b_hh[1 * HN + l]) * LOG2E;
    const float bias_g = (b_ih[2 * HN + l] + b_hh[2 * HN + l]) * (2.0f * LOG2E);
    const float bias_o = (b_ih[3 * HN + l] + b_hh[3 * HN + l]) * LOG2E;
    const float wfc = W_fc[l];
    const float bfc = b_fc[0];

    const bool rb0 = (rg & 1) != 0;   // tile-select bits
    const bool rb1 = (rg & 2) != 0;

    const float* xb = x   + (size_t)b * TLEN * 4;
    float*       ob = out + (size_t)b * TLEN;

    float h = 0.0f, c = 0.0f;
    const float4v zf = {0.0f, 0.0f, 0.0f, 0.0f};

    // ---- x stage: lane l holds x[t0 + l] (16B coalesced per chunk) ----
    float4 xcur = *(const float4*)(xb + (size_t)l * 4);   // chunk 0

    for (int ci = 0; ci < TLEN / 64; ++ci) {
        const int cn = (ci < TLEN / 64 - 1) ? ci + 1 : ci;
        float4 xnext = *(const float4*)(xb + (size_t)(cn * 64 + l) * 4);

        const int xq0 = __builtin_bit_cast(int, __builtin_amdgcn_cvt_pkrtz(xcur.x, xcur.y));
        const int xq1 = __builtin_bit_cast(int, __builtin_amdgcn_cvt_pkrtz(xcur.z, xcur.w));

        for (int s = 0; s < 64; ++s) {
            // ---- A fragments: broadcast h k-slices (2 uniform b128) ----
            const half8v a0 = *(const half8v*)&hbuf[rg * 8];
            const half8v a1 = *(const half8v*)&hbuf[32 + rg * 8];

            // ---- x broadcast + x-dot chains (fill the read latency) ----
            const int xi0 = __builtin_amdgcn_readlane(xq0, s);
            const int xi1 = __builtin_amdgcn_readlane(xq1, s);
            const half2v xh0 = __builtin_bit_cast(half2v, xi0);
            const half2v xh1 = __builtin_bit_cast(half2v, xi1);

            float ai = __builtin_amdgcn_fdot2(wip0, xh0, bias_i, false);
            float af = __builtin_amdgcn_fdot2(wfp0, xh0, bias_f, false);
            float ag = __builtin_amdgcn_fdot2(wgp0, xh0, bias_g, false);
            float ao = __builtin_amdgcn_fdot2(wop0, xh0, bias_o, false);
            ai = __builtin_amdgcn_fdot2(wip1, xh1, ai, false);
            af = __builtin_amdgcn_fdot2(wfp1, xh1, af, false);
            ag = __builtin_amdgcn_fdot2(wgp1, xh1, ag, false);
            ao = __builtin_amdgcn_fdot2(wop1, xh1, ao, false);

#define MM(t) \
            float4v d##t = __builtin_amdgcn_mfma_f32_16x16x32_f16(a0, wb##t##_0, zf, 0, 0, 0); \
            d##t = __builtin_amdgcn_mfma_f32_16x16x32_f16(a1, wb##t##_1, d##t, 0, 0, 0);

            // ---- groups 0,1 issued up front: pipe primed 16 deep ----
            MM(0) MM(1) MM(2) MM(3)            // gate i tiles
            MM(4) MM(5) MM(6) MM(7)            // gate f tiles

            // ---- sigmoid-i while groups 1.. crunch (needs d0-3 only) ----
            {
                const float i01 = rb0 ? d1[0] : d0[0];
                const float i23 = rb0 ? d3[0] : d2[0];
                ai += rb1 ? i23 : i01;
            }
            float si = __builtin_amdgcn_rcpf(1.0f + __builtin_amdgcn_exp2f(-ai));

            MM(8) MM(9) MM(10) MM(11)          // gate g tiles

            // ---- sigmoid-f (needs d4-7) ----
            {
                const float f01 = rb0 ? d5[0] : d4[0];
                const float f23 = rb0 ? d7[0] : d6[0];
                af += rb1 ? f23 : f01;
            }
            float sf = __builtin_amdgcn_rcpf(1.0f + __builtin_amdgcn_exp2f(-af));

            MM(12) MM(13) MM(14) MM(15)        // gate o tiles
#undef MM

            // ---- tanh-g (needs d8-11) ----
            {
                const float g01 = rb0 ? d9[0]  : d8[0];
                const float g23 = rb0 ? d11[0] : d10[0];
                ag += rb1 ? g23 : g01;
            }
            float tg = 1.0f - 2.0f * __builtin_amdgcn_rcpf(
                                         1.0f + __builtin_amdgcn_exp2f(ag));

            // ---- tail: o-select + c/h chain (after last tile) ----
            {
                const float o01 = rb0 ? d13[0] : d12[0];
                const float o23 = rb0 ? d15[0] : d14[0];
                ao += rb1 ? o23 : o01;
            }
            float so = __builtin_amdgcn_rcpf(1.0f + __builtin_amdgcn_exp2f(-ao));

            c = sf * c + si * tg;
            float th = 1.0f - 2.0f * __builtin_amdgcn_rcpf(
                           1.0f + __builtin_amdgcn_exp2f(c * (2.0f * LOG2E)));
            h = so * th;

            // ---- publish h (f16 RTZ) + FC partial ----
            const int hpk = __builtin_bit_cast(int,
                                __builtin_amdgcn_cvt_pkrtz(h, h));
            hbuf[l] = (unsigned short)(hpk & 0xffff);
            ring[s][l] = h * wfc;
        }

        // ---- FC: transposed reduce + coalesced 64-wide store ----
        __syncthreads();   // single wave: orders LDS w->r
        float s0 = 0.f, s1 = 0.f, s2 = 0.f, s3 = 0.f;
#pragma unroll
        for (int k = 0; k < HN; k += 4) {
            s0 += ring[l][k];
            s1 += ring[l][k + 1];
            s2 += ring[l][k + 2];
            s3 += ring[l][k + 3];
        }
        ob[ci * 64 + l] = (s0 + s1) + (s2 + s3) + bfc;

        xcur = xnext;
    }
}

extern "C" void kernel_launch(void* const* d_in, const int* in_sizes, int n_in,
                              void* d_out, int out_size, void* d_ws, size_t ws_size,
                              hipStream_t stream) {
    const float* x    = (const float*)d_in[0];
    const float* W_ih = (const float*)d_in[1];
    const float* W_hh = (const float*)d_in[2];
    const float* b_ih = (const float*)d_in[3];
    const float* b_hh = (const float*)d_in[4];
    const float* W_fc = (const float*)d_in[5];
    const float* b_fc = (const float*)d_in[6];
    float* out = (float*)d_out;

    const int B = in_sizes[0] / (TLEN * 4);   // 1024
    lstm_mfma3<<<dim3(B), dim3(64), 0, stream>>>(
        x, W_ih, W_hh, b_ih, b_hh, W_fc, b_fc, out);
}